// Round 9
// baseline (213.891 us; speedup 1.0000x reference)
//
#include <hip/hip_runtime.h>
#include <hip/hip_bf16.h>
#include <cmath>
#include <cstddef>

#define N 8192
#define D 256
#define BI 128
#define NT (N / BI)        // 64 row tiles
#define NTRI (NT * (NT + 1) / 2)   // 2080 upper-triangle tiles

typedef __attribute__((ext_vector_type(8))) short short8;   // 8 bf16 = one MFMA A/B frag
typedef __attribute__((ext_vector_type(4))) float float4v;  // MFMA C/D frag

__device__ inline ushort f2bf(float x) {
    __hip_bfloat16 h = __float2bfloat16(x);
    return __builtin_bit_cast(ushort, h);
}
__device__ inline float bf2f(ushort u) {
    __hip_bfloat16 h = __builtin_bit_cast(__hip_bfloat16, u);
    return __bfloat162float(h);
}

// sortable pack: (monotone-uint(key) << 32) | idx  -> atomicMin == argmin, lowest-idx tie-break
__device__ inline unsigned long long packKI(float k, int idx) {
    unsigned u = __float_as_uint(k);
    u = (u & 0x80000000u) ? ~u : (u | 0x80000000u);
    return ((unsigned long long)u << 32) | (unsigned)idx;
}

// T(t) = tiles before row t in row-major upper triangle (incl. diagonal), NT=64
__device__ inline int triT(int t) { return t * (129 - t) / 2; }

// Frag-packed layout (ushort units): element (row, k) lives at
//   ((row/16)*32 + k/8)*128 + (row%16)*8 + (k%8)
// so one MFMA frag (row fixed, 8 consecutive k) is 16 contiguous bytes and a
// wave's 64 frag loads (tx x q) are 1 KB fully contiguous.

// ---------------- K1: fused prep — copies, sqnorm, M init, frag-packed bf16 hi/lo split ----
__global__ void prep_kernel(const float4* __restrict__ a, const float4* __restrict__ p,
                            float4* __restrict__ out, float* __restrict__ sq,
                            ushort* __restrict__ Phi, ushort* __restrict__ Plo,
                            unsigned long long* __restrict__ M) {
    const int gsz = gridDim.x * blockDim.x;          // 262144, multiple of 64
    const int g0 = blockIdx.x * blockDim.x + threadIdx.x;
    const int total = N * D / 4;                     // 524288 float4

    // pass 1: copy e_actv -> out + per-row sqnorm (one row per wave per iter)
    for (int idx = g0; idx < total; idx += gsz) {
        float4 v = a[idx];
        out[idx] = v;
        float s = v.x * v.x + v.y * v.y + v.z * v.z + v.w * v.w;
        #pragma unroll
        for (int off = 32; off; off >>= 1) s += __shfl_down(s, off);
        if ((threadIdx.x & 63) == 0) sq[idx >> 6] = s;
    }
    // pass 2: copy e_ap into second output slot
    for (int idx = g0; idx < total; idx += gsz) out[total + idx] = p[idx];

    // pass 3: frag-packed hi/lo split. o indexes ushort8 (16 B) slots of the
    // packed arrays; writes are fully coalesced, reads are 32 B per thread
    // grouped into 128-B row segments per wave.
    const int tot8 = N * D / 8;                      // 262144
    for (int o = g0; o < tot8; o += gsz) {
        int tx = o & 15;
        int gc = o >> 4;
        int c  = gc & 31;        // k-chunk (8 bf16)
        int g  = gc >> 5;        // row group
        int row = g * 16 + tx;
        const float4* src = &a[row * 64 + c * 2];
        float4 v0 = src[0], v1 = src[1];
        short8 h, l;
        float f;
        f = v0.x; h[0] = (short)f2bf(f); l[0] = (short)f2bf(f - bf2f((ushort)h[0]));
        f = v0.y; h[1] = (short)f2bf(f); l[1] = (short)f2bf(f - bf2f((ushort)h[1]));
        f = v0.z; h[2] = (short)f2bf(f); l[2] = (short)f2bf(f - bf2f((ushort)h[2]));
        f = v0.w; h[3] = (short)f2bf(f); l[3] = (short)f2bf(f - bf2f((ushort)h[3]));
        f = v1.x; h[4] = (short)f2bf(f); l[4] = (short)f2bf(f - bf2f((ushort)h[4]));
        f = v1.y; h[5] = (short)f2bf(f); l[5] = (short)f2bf(f - bf2f((ushort)h[5]));
        f = v1.z; h[6] = (short)f2bf(f); l[6] = (short)f2bf(f - bf2f((ushort)h[6]));
        f = v1.w; h[7] = (short)f2bf(f); l[7] = (short)f2bf(f - bf2f((ushort)h[7]));
        *(short8*)&Phi[(size_t)o * 8] = h;
        *(short8*)&Plo[(size_t)o * 8] = l;
    }
    // M init
    for (int i = g0; i < N; i += gsz) M[i] = 0xFFFFFFFFFFFFFFFFull;
}

// ---------------- K2: symmetric split-bf16 MFMA, LDS-free K-loop, dual-sided argmin ----------------
// Frags load straight from the frag-packed global arrays (L2-resident): no LDS
// staging, no barriers, no vmcnt(0) drains, no bank conflicts in the K-loop.
__launch_bounds__(256)
__global__ void argmin_sym(const ushort* __restrict__ Phi, const ushort* __restrict__ Plo,
                           const int* __restrict__ host, const float* __restrict__ sq,
                           unsigned long long* __restrict__ M) {
    // decode linear tile id -> (ti, tj), ti <= tj
    const int b = blockIdx.x;
    int ti = (int)floor(64.5 - sqrt(64.5 * 64.5 - 2.0 * (double)b));
    while (triT(ti + 1) <= b) ti++;
    while (triT(ti) > b) ti--;
    const int tj = ti + (b - triT(ti));

    __shared__ float sqA_s[BI], sqB_s[BI];
    __shared__ int   hostB_s[BI];
    __shared__ float rowV[2 * BI], colV[2 * BI];
    __shared__ int   rowI[2 * BI], colI[2 * BI];

    const int ib0 = ti * BI;
    const int jb0 = tj * BI;
    const int tid = threadIdx.x;
    const int lane = tid & 63;
    const int wave = tid >> 6;      // 0..3
    const int wrow = wave >> 1;     // 0..1
    const int wcol = wave & 1;      // 0..1
    const int tx = lane & 15;       // 0..15
    const int q  = lane >> 4;       // 0..3

    if (tid < BI) {
        sqA_s[tid] = sq[ib0 + tid];
        sqB_s[tid] = sq[jb0 + tid];
        hostB_s[tid] = host[jb0 + tid];
    }

    // hostA packed per rt: 4 bytes = hosts of rows (rt,reg) for this lane (host < 64)
    unsigned hostAp[4];
    #pragma unroll
    for (int rt = 0; rt < 4; rt++) {
        unsigned p = 0;
        #pragma unroll
        for (int reg = 0; reg < 4; reg++) {
            int hv = host[ib0 + wrow * 64 + rt * 16 + q * 4 + reg];
            p |= ((unsigned)hv & 0xFFu) << (8 * reg);
        }
        hostAp[rt] = p;
    }
    __syncthreads();   // sq/host staged before epilogue reads (K-loop doesn't touch LDS)

    float4v acc[4][4];   // [rt][ct]
    #pragma unroll
    for (int rt = 0; rt < 4; rt++)
        #pragma unroll
        for (int ct = 0; ct < 4; ct++) acc[rt][ct] = (float4v)(0.0f);

    const int ga = (ib0 >> 4) + wrow * 4;   // A row-groups for this wave
    const int gb = (jb0 >> 4) + wcol * 4;   // B row-groups for this wave
    const int txo = tx * 8;

    // 8 k32 slices; per-acc MFMA order (ascending slice, hh->hl->lh) identical
    // to the verified R8 kernel -> bit-exact keys.
    #pragma unroll 2
    for (int s = 0; s < 8; s++) {
        const int c0 = s * 4 + q;           // this lane's k-chunk within the slice
        short8 ah[4], al[4], bh[4], bl[4];
        #pragma unroll
        for (int rt = 0; rt < 4; rt++) {
            int o = ((ga + rt) * 32 + c0) * 128 + txo;
            ah[rt] = *(const short8*)&Phi[o];
            al[rt] = *(const short8*)&Plo[o];
        }
        #pragma unroll
        for (int ct = 0; ct < 4; ct++) {
            int o = ((gb + ct) * 32 + c0) * 128 + txo;
            bh[ct] = *(const short8*)&Phi[o];
            bl[ct] = *(const short8*)&Plo[o];
        }
        #pragma unroll
        for (int rt = 0; rt < 4; rt++)
            #pragma unroll
            for (int ct = 0; ct < 4; ct++)
                acc[rt][ct] = __builtin_amdgcn_mfma_f32_16x16x32_bf16(ah[rt], bh[ct], acc[rt][ct], 0, 0, 0);
        #pragma unroll
        for (int rt = 0; rt < 4; rt++)
            #pragma unroll
            for (int ct = 0; ct < 4; ct++)
                acc[rt][ct] = __builtin_amdgcn_mfma_f32_16x16x32_bf16(ah[rt], bl[ct], acc[rt][ct], 0, 0, 0);
        #pragma unroll
        for (int rt = 0; rt < 4; rt++)
            #pragma unroll
            for (int ct = 0; ct < 4; ct++)
                acc[rt][ct] = __builtin_amdgcn_mfma_f32_16x16x32_bf16(al[rt], bh[ct], acc[rt][ct], 0, 0, 0);
    }

    // ---- epilogue: dual-sided argmin (same as verified R8) ----
    // rows side: for each of this lane's 16 rows, min over its 4 ct entries, then over tx
    #pragma unroll
    for (int rt = 0; rt < 4; rt++) {
        unsigned hp = hostAp[rt];
        #pragma unroll
        for (int reg = 0; reg < 4; reg++) {
            int il = wrow * 64 + rt * 16 + q * 4 + reg;
            int ig = ib0 + il;
            int ha = (int)((hp >> (8 * reg)) & 0xFFu);
            float v = 3.0e38f; int ix = 0x7fffffff;
            #pragma unroll
            for (int ct = 0; ct < 4; ct++) {
                int jl = wcol * 64 + ct * 16 + tx;
                int jg = jb0 + jl;
                float key = sqB_s[jl] - 2.0f * acc[rt][ct][reg];
                bool masked = (hostB_s[jl] == ha) || (jg == ig);
                if (!masked && (key < v || (key == v && jg < ix))) { v = key; ix = jg; }
            }
            #pragma unroll
            for (int d = 1; d < 16; d <<= 1) {
                float ov = __shfl_xor(v, d);
                int   oi = __shfl_xor(ix, d);
                if (ov < v || (ov == v && oi < ix)) { v = ov; ix = oi; }
            }
            if (tx == 0) { rowV[il * 2 + wcol] = v; rowI[il * 2 + wcol] = ix; }
        }
    }

    // cols side (off-diagonal only): per lane's 4 cols, min over 16 row entries, then over q
    if (ti != tj) {
        #pragma unroll
        for (int ct = 0; ct < 4; ct++) {
            int jl = wcol * 64 + ct * 16 + tx;
            int hb = hostB_s[jl];
            float v = 3.0e38f; int ix = 0x7fffffff;
            #pragma unroll
            for (int rt = 0; rt < 4; rt++) {
                unsigned hp = hostAp[rt];
                #pragma unroll
                for (int reg = 0; reg < 4; reg++) {
                    int il = wrow * 64 + rt * 16 + q * 4 + reg;
                    int ig = ib0 + il;
                    bool masked = ((int)((hp >> (8 * reg)) & 0xFFu) == hb);
                    float key = sqA_s[il] - 2.0f * acc[rt][ct][reg];
                    if (!masked && (key < v || (key == v && ig < ix))) { v = key; ix = ig; }
                }
            }
            #pragma unroll
            for (int d = 16; d < 64; d <<= 1) {
                float ov = __shfl_xor(v, d);
                int   oi = __shfl_xor(ix, d);
                if (ov < v || (ov == v && oi < ix)) { v = ov; ix = oi; }
            }
            if (q == 0) { colV[jl * 2 + wrow] = v; colI[jl * 2 + wrow] = ix; }
        }
    }

    __syncthreads();
    if (tid < BI) {
        float v0 = rowV[tid * 2];     int x0 = rowI[tid * 2];
        float v1 = rowV[tid * 2 + 1]; int x1 = rowI[tid * 2 + 1];
        if (v1 < v0 || (v1 == v0 && x1 < x0)) { v0 = v1; x0 = x1; }
        atomicMin(&M[ib0 + tid], packKI(v0, x0));
        if (ti != tj) {
            float w0 = colV[tid * 2];     int y0 = colI[tid * 2];
            float w1 = colV[tid * 2 + 1]; int y1 = colI[tid * 2 + 1];
            if (w1 < w0 || (w1 == w0 && y1 < y0)) { w0 = w1; y0 = y1; }
            atomicMin(&M[jb0 + tid], packKI(w0, y0));
        }
    }
}

// ---------------- K3: extract index and gather e_an rows ----------------
__global__ void finalize_kernel(const unsigned long long* __restrict__ M,
                                const float* __restrict__ E, float* __restrict__ out_an) {
    int row = blockIdx.x;
    int t = threadIdx.x;   // 64
    int idx = (int)(unsigned)(M[row] & 0xFFFFFFFFull);
    float4 v = *(const float4*)&E[(size_t)idx * D + t * 4];
    *(float4*)&out_an[(size_t)row * D + t * 4] = v;
}

extern "C" void kernel_launch(void* const* d_in, const int* in_sizes, int n_in,
                              void* d_out, int out_size, void* d_ws, size_t ws_size,
                              hipStream_t stream) {
    const float* e_actv = (const float*)d_in[0];
    const float* e_ap   = (const float*)d_in[1];
    const int*   host   = (const int*)d_in[2];
    float* out = (float*)d_out;

    // workspace: M u64[N] | sq f32[N] | Phi bf16[N*D] packed | Plo bf16[N*D] packed  (~8.1 MB)
    unsigned long long* M = (unsigned long long*)d_ws;
    float*  sq  = (float*)(M + N);
    ushort* Phi = (ushort*)(sq + N);
    ushort* Plo = Phi + (size_t)N * D;

    prep_kernel<<<1024, 256, 0, stream>>>(
        (const float4*)e_actv, (const float4*)e_ap, (float4*)out,
        sq, Phi, Plo, M);
    argmin_sym<<<NTRI, 256, 0, stream>>>(Phi, Plo, host, sq, M);
    finalize_kernel<<<N, 64, 0, stream>>>(M, e_actv, out + 2 * (size_t)N * D);
}